// Round 2
// baseline (9997.083 us; speedup 1.0000x reference)
//
#include <hip/hip_runtime.h>
#include <hip/hip_bf16.h>

// Sizes (compile-time constants from the reference)
#define BB 8
#define LL 512
#define DD 64
#define HH 8
#define NG 64
#define NEGV (-1e9f)
#define BIGV (1e9f)

__device__ __forceinline__ float wred_max(float v){
  #pragma unroll
  for(int off=32;off>0;off>>=1) v = fmaxf(v, __shfl_xor(v, off, 64));
  return v;
}
__device__ __forceinline__ float wred_sum(float v){
  #pragma unroll
  for(int off=32;off>0;off>>=1) v += __shfl_xor(v, off, 64);
  return v;
}

// K0: unary = (x + sinusoidal_pe) * m1 ; qzstate = unary
__global__ void k0_init(const float* __restrict__ x, const int* __restrict__ mask,
                        float* __restrict__ unary, float* __restrict__ qzstate){
  int idx = blockIdx.x*256 + threadIdx.x;       // < B*L*64
  int d = idx & 63; int row = idx >> 6;         // row in [0, B*L)
  int pos = row & (LL-1);
  int k2 = d & ~1;
  // ln(10000)/64 = 0.14391156962f
  float div = __expf(-(float)k2 * 0.14391156962f);
  float arg = (float)pos * div;
  float pe = (d & 1) ? cosf(arg) : sinf(arg);
  float mk = (mask[row] != 0) ? 1.f : 0.f;
  float u = (x[idx] + pe) * mk;
  unary[idx] = u; qzstate[idx] = u;
}

// K1: qz = softmax over last dim (64) of qzstate, times row mask
__global__ void k1_softmax64(const float* __restrict__ qzstate, const int* __restrict__ mask,
                             float* __restrict__ qz){
  int t = threadIdx.x; int lane = t & 63; int w = t >> 6;
  int row = blockIdx.x*4 + w;                   // [0, B*L)
  float v = qzstate[(size_t)row*64 + lane];
  float mx = wred_max(v);
  float e = __expf(v - mx);
  float s = wred_sum(e);
  float mk = (mask[row] != 0) ? 1.f : 0.f;
  qz[(size_t)row*64 + lane] = e / s * mk;
}

// K2: t1[(z*8+c)*512 + i][b] = sum_a qz[z,i,a] * T[a,b,c]
__global__ void k2_t1(const float* __restrict__ qz, const float* __restrict__ ternary,
                      float* __restrict__ t1){
  int bid = blockIdx.x;                 // (z*8+c)*8 + itile
  int itile = bid & 7; int c = (bid>>3) & 7; int z = bid >> 6;
  int i0 = itile*64;
  int t = threadIdx.x; int lane = t & 63; int w = t >> 6;
  __shared__ float Ts[64][64];          // Ts[a][b]
  __shared__ float Qs[64][64];          // Qs[r][a]
  #pragma unroll
  for(int m=0;m<16;m++){
    int e = t + 256*m; int a = e>>6, b = e&63;
    Ts[a][b] = ternary[((size_t)a*64 + b)*8 + c];
    Qs[a][b] = qz[((size_t)z*LL + i0 + a)*64 + b];
  }
  __syncthreads();
  #pragma unroll
  for(int m=0;m<16;m++){
    int r = 4*m + w;
    float s = 0.f;
    for(int a=0;a<64;a++) s += Qs[r][a] * Ts[a][lane];
    t1[((size_t)(z*8+c)*LL + i0 + r)*64 + lane] = s;
  }
}

// K3: F1 row-tile (16 rows x 512 cols) + mask/diag + row softmax -> P (per z-group)
__global__ void k3_f1_softmax(const float* __restrict__ t1, const float* __restrict__ qz,
                              const int* __restrict__ mask, float* __restrict__ P, int zbase){
  int bid = blockIdx.x;                 // ((zg*8 + c)*32 + itile)
  int itile = bid & 31; int c = (bid>>5) & 7; int zg = bid >> 8; int z = zbase + zg;
  int i0 = itile*16;
  int t = threadIdx.x; int lane = t & 63; int w = t >> 6;
  __shared__ float t1s[16][64];
  __shared__ float qzl[64][65];         // padded: read qzl[lane][b]
  #pragma unroll
  for(int m=0;m<4;m++){
    int e = t + 256*m; int r = e>>6, b = e&63;
    t1s[r][b] = t1[((size_t)(z*8+c)*LL + i0 + r)*64 + b];
  }
  float acc[4][8];
  #pragma unroll
  for(int m=0;m<4;m++)
    #pragma unroll
    for(int jt=0;jt<8;jt++) acc[m][jt] = 0.f;
  #pragma unroll
  for(int jt=0;jt<8;jt++){
    __syncthreads();
    #pragma unroll
    for(int m=0;m<16;m++){               // FIXED: 64x64 tile needs 16 passes of 256 threads
      int e = t + 256*m; int jl = e>>6, a = e&63;
      qzl[jl][a] = qz[((size_t)z*LL + jt*64 + jl)*64 + a];
    }
    __syncthreads();
    for(int b=0;b<64;b++){
      float qv = qzl[lane][b];
      #pragma unroll
      for(int m=0;m<4;m++) acc[m][jt] += t1s[w + 4*m][b] * qv;
    }
  }
  int cv[8];
  #pragma unroll
  for(int jt=0;jt<8;jt++) cv[jt] = mask[z*LL + jt*64 + lane];
  #pragma unroll
  for(int m=0;m<4;m++){
    int il = w + 4*m; int ig = i0 + il;
    int rvalid = mask[z*LL + ig];
    float mx = -3e38f;
    #pragma unroll
    for(int jt=0;jt<8;jt++){
      int jg = jt*64 + lane;
      float v;
      if(rvalid && cv[jt]) v = acc[m][jt] - ((ig==jg) ? BIGV : 0.f);
      else v = NEGV;
      acc[m][jt] = v; mx = fmaxf(mx, v);
    }
    mx = wred_max(mx);
    float s = 0.f;
    #pragma unroll
    for(int jt=0;jt<8;jt++){ float e = __expf(acc[m][jt] - mx); acc[m][jt] = e; s += e; }
    s = wred_sum(s);
    float inv = 1.f / s;
    #pragma unroll
    for(int jt=0;jt<8;jt++)
      P[((size_t)(zg*8+c)*LL + ig)*LL + jt*64 + lane] = acc[m][jt]*inv;
  }
}

// K4: P2[z,i,j] = softmax_j( sum_a qz[z,i,a] * G[j,a] )   (j over 64 globals)
__global__ void k4_p2(const float* __restrict__ qz, const float* __restrict__ gw,
                      float* __restrict__ P2){
  int t = threadIdx.x; int lane = t & 63; int w = t >> 6;
  int row = blockIdx.x*4 + w;           // [0, B*L)
  __shared__ float Gs[64][65];
  #pragma unroll
  for(int m=0;m<16;m++){ int e = t + 256*m; int j = e>>6, a = e&63; Gs[j][a] = gw[(size_t)j*64 + a]; }
  __syncthreads();
  float qv = qz[(size_t)row*64 + lane];
  float s = 0.f;
  for(int a=0;a<64;a++){
    float q = __shfl(qv, a, 64);
    s += q * Gs[lane][a];
  }
  float mx = wred_max(s);
  float e = __expf(s - mx);
  float sum = wred_sum(e);
  P2[(size_t)row*64 + lane] = e / sum;
}

// K5a: per (zg,c): out = op(P) @ qz ; M=512, N=64, K=512.  TRANSA=0 -> mi, 1 -> mj
template<int TRANSA>
__global__ void k5a_gemm(const float* __restrict__ P, const float* __restrict__ qz,
                         float* __restrict__ out, int zbase){
  int bid = blockIdx.x;                 // (zg*8 + c)*8 + mtile
  int mtile = bid & 7; int c = (bid>>3) & 7; int zg = bid >> 6; int z = zbase + zg;
  int i0 = mtile*64;
  int t = threadIdx.x; int lane = t & 63; int w = t >> 6;
  __shared__ float As[64][65];          // padded (transpose store path)
  __shared__ float Bs[64][64];
  float acc[16];
  #pragma unroll
  for(int m=0;m<16;m++) acc[m] = 0.f;
  const float* Pz = P + (size_t)(zg*8+c)*LL*LL;
  for(int kt=0;kt<8;kt++){
    __syncthreads();
    #pragma unroll
    for(int m=0;m<16;m++){
      int e = t + 256*m; int r = e>>6, col = e&63;
      if(TRANSA) As[col][r] = Pz[(size_t)(kt*64 + r)*LL + i0 + col]; // A[m][k] = P[k][m]
      else       As[r][col] = Pz[(size_t)(i0 + r)*LL + kt*64 + col]; // A[m][k] = P[m][k]
      Bs[r][col] = qz[((size_t)z*LL + kt*64 + r)*64 + col];
    }
    __syncthreads();
    for(int k=0;k<64;k++){
      float bv = Bs[k][lane];
      #pragma unroll
      for(int m=0;m<16;m++) acc[m] += As[w + 4*m][k] * bv;
    }
  }
  #pragma unroll
  for(int m=0;m<16;m++)
    out[((size_t)(zg*8+c)*LL + i0 + w + 4*m)*64 + lane] = acc[m];
}

// K5b: new_qz = (unary + Mi + Mj + Mg) * m1
__global__ void k5b_combine(const float* __restrict__ mi, const float* __restrict__ mj,
                            const float* __restrict__ P2, const float* __restrict__ ternary,
                            const float* __restrict__ gw, const float* __restrict__ unary,
                            const int* __restrict__ mask, float* __restrict__ outq, int zbase){
  int bid = blockIdx.x;                 // zg*32 + itile
  int itile = bid & 31; int zg = bid >> 5; int z = zbase + zg;
  int i0 = itile*16;
  int t = threadIdx.x; int lane = t & 63; int w = t >> 6;
  __shared__ float Ts[64][65];
  __shared__ float mis[16][64];
  __shared__ float mjs[16][64];
  float ai[4] = {0,0,0,0}, aj[4] = {0,0,0,0};
  for(int c=0;c<8;c++){
    __syncthreads();
    #pragma unroll
    for(int m=0;m<16;m++){
      int e = t + 256*m; int a = e>>6, b = e&63;
      Ts[a][b] = ternary[((size_t)a*64 + b)*8 + c];
    }
    #pragma unroll
    for(int m=0;m<4;m++){
      int e = t + 256*m; int r = e>>6, b = e&63;
      mis[r][b] = mi[((size_t)(zg*8+c)*LL + i0 + r)*64 + b];
      mjs[r][b] = mj[((size_t)(zg*8+c)*LL + i0 + r)*64 + b];
    }
    __syncthreads();
    #pragma unroll
    for(int m=0;m<4;m++){
      int r = w + 4*m;
      float si = 0.f, sj = 0.f;
      for(int k=0;k<64;k++){
        si += mis[r][k] * Ts[lane][k];   // Mi[a=lane] += mi[b]*T[a][b]
        sj += mjs[r][k] * Ts[k][lane];   // Mj[b=lane] += mj[a]*T[a][b]
      }
      ai[m] += si; aj[m] += sj;
    }
  }
  __syncthreads();
  #pragma unroll
  for(int m=0;m<16;m++){ int e = t + 256*m; int j = e>>6, a = e&63; Ts[j][a] = gw[(size_t)j*64 + a]; }
  #pragma unroll
  for(int m=0;m<4;m++){
    int e = t + 256*m; int r = e>>6, jj = e&63;
    mis[r][jj] = P2[((size_t)z*LL + i0 + r)*64 + jj];
  }
  __syncthreads();
  #pragma unroll
  for(int m=0;m<4;m++){
    int r = w + 4*m; int ig = i0 + r;
    float g = 0.f;
    for(int j=0;j<64;j++) g += mis[r][j] * Ts[j][lane];
    float mk = (mask[z*LL + ig] != 0) ? 1.f : 0.f;
    size_t idx = ((size_t)z*LL + ig)*64 + lane;
    outq[idx] = (unary[idx] + ai[m] + aj[m] + g) * mk;
  }
}

extern "C" void kernel_launch(void* const* d_in, const int* in_sizes, int n_in,
                              void* d_out, int out_size, void* d_ws, size_t ws_size,
                              hipStream_t stream) {
  const float* x       = (const float*)d_in[0];
  const int*   mask    = (const int*)d_in[1];
  const float* ternary = (const float*)d_in[2];
  const float* gw      = (const float*)d_in[3];
  float* out = (float*)d_out;

  const size_t NE = (size_t)BB*LL*DD;        // 262144
  const size_t T1E = (size_t)BB*HH*LL*64;    // 2097152
  const size_t PE_Z = (size_t)HH*LL*LL;      // 2097152 per z
  const size_t MI_Z = (size_t)HH*LL*64;      // 262144 per z

  float* ws = (float*)d_ws;
  float* unary   = ws;
  float* qzstate = unary + NE;
  float* qz      = qzstate + NE;
  float* P2      = qz + NE;
  float* t1      = P2 + NE;
  float* P       = t1 + T1E;

  long long fixed = (long long)(NE*4 + T1E);
  long long per_z = (long long)(PE_Z + 2*MI_Z);
  long long avail = (long long)(ws_size/4) - fixed;
  int g = (int)(avail / per_z);
  if(g > 8) g = 8; if(g < 1) g = 1;

  float* mi = P + (size_t)g*PE_Z;
  float* mj = mi + (size_t)g*MI_Z;

  k0_init<<<(int)(NE/256), 256, 0, stream>>>(x, mask, unary, qzstate);
  for(int it=0; it<4; ++it){
    k1_softmax64<<<(BB*LL)/4, 256, 0, stream>>>(qzstate, mask, qz);
    k2_t1<<<BB*HH*8, 256, 0, stream>>>(qz, ternary, t1);
    k4_p2<<<(BB*LL)/4, 256, 0, stream>>>(qz, gw, P2);
    float* outq = (it==3) ? out : qzstate;
    for(int zbase=0; zbase<BB; zbase+=g){
      int gg = (BB - zbase < g) ? (BB - zbase) : g;
      k3_f1_softmax<<<gg*HH*32, 256, 0, stream>>>(t1, qz, mask, P, zbase);
      k5a_gemm<0><<<gg*HH*8, 256, 0, stream>>>(P, qz, mi, zbase);
      k5a_gemm<1><<<gg*HH*8, 256, 0, stream>>>(P, qz, mj, zbase);
      k5b_combine<<<gg*32, 256, 0, stream>>>(mi, mj, P2, ternary, gw, unary, mask, outq, zbase);
    }
  }
}

// Round 3
// 480.215 us; speedup vs baseline: 20.8179x; 20.8179x over previous
//
#include <hip/hip_runtime.h>

#define BB 8
#define LL 512
#define HH 8
#define NEGV (-1e9f)
#define BIGV (1e9f)

typedef unsigned short u16;
typedef __attribute__((ext_vector_type(8))) short bf16x8;
typedef __attribute__((ext_vector_type(4))) float f32x4;

#define MFMA(a,b,c) __builtin_amdgcn_mfma_f32_16x16x32_bf16(a,b,c,0,0,0)

__device__ __forceinline__ u16 f2b(float f){
  unsigned u = __float_as_uint(f);
  u = (u + 0x7fffu + ((u>>16)&1u)) >> 16;
  return (u16)u;
}
__device__ __forceinline__ float b2f(u16 s){ return __uint_as_float(((unsigned)s)<<16); }
__device__ __forceinline__ bf16x8 ldb8(const u16* p){ return *(const bf16x8*)p; }

__device__ __forceinline__ float wred_max(float v){
  #pragma unroll
  for(int off=32;off>0;off>>=1) v = fmaxf(v, __shfl_xor(v, off, 64));
  return v;
}
__device__ __forceinline__ float wred_sum(float v){
  #pragma unroll
  for(int off=32;off>0;off>>=1) v += __shfl_xor(v, off, 64);
  return v;
}
__device__ __forceinline__ float g16_max(float v){
  v = fmaxf(v, __shfl_xor(v,1,64)); v = fmaxf(v, __shfl_xor(v,2,64));
  v = fmaxf(v, __shfl_xor(v,4,64)); v = fmaxf(v, __shfl_xor(v,8,64));
  return v;
}
__device__ __forceinline__ float g16_sum(float v){
  v += __shfl_xor(v,1,64); v += __shfl_xor(v,2,64);
  v += __shfl_xor(v,4,64); v += __shfl_xor(v,8,64);
  return v;
}

// ---- prep: bf16 transposed ternary tables (once per call) ----
// T4t[c][b][a], T2t[a][c*64+b], T3t[b][c*64+a], Gt[a][j]
__global__ void kp_prep(const float* __restrict__ T, const float* __restrict__ gw,
                        u16* __restrict__ T4t, u16* __restrict__ T2t,
                        u16* __restrict__ T3t, u16* __restrict__ Gt){
  int idx = blockIdx.x*256 + threadIdx.x;   // < 32768
  { int c=idx>>12, b=(idx>>6)&63, a=idx&63; T4t[idx] = f2b(T[(a*64+b)*8+c]); }
  { int a=idx>>9,  c=(idx>>6)&7,  b=idx&63; T2t[idx] = f2b(T[(a*64+b)*8+c]); }
  { int b=idx>>9,  c=(idx>>6)&7,  a=idx&63; T3t[idx] = f2b(T[(a*64+b)*8+c]); }
  if(idx < 4096){ int a=idx>>6, j=idx&63; Gt[idx] = f2b(gw[j*64+a]); }
}

// ---- k0: unary = (x + pe) * m1 ; qzstate = unary ----
__global__ void k0_init(const float* __restrict__ x, const int* __restrict__ mask,
                        float* __restrict__ unary, float* __restrict__ qzstate){
  int idx = blockIdx.x*256 + threadIdx.x;
  int d = idx & 63; int row = idx >> 6;
  int pos = row & (LL-1);
  int k2 = d & ~1;
  float div = __expf(-(float)k2 * 0.14391156962f);  // ln(10000)/64
  float arg = (float)pos * div;
  float pe = (d & 1) ? cosf(arg) : sinf(arg);
  float mk = (mask[row] != 0) ? 1.f : 0.f;
  float u = (x[idx] + pe) * mk;
  unary[idx] = u; qzstate[idx] = u;
}

// ---- k1: qz = softmax64(qzstate) * m1 -> bf16 ----
__global__ void k1_softmax64(const float* __restrict__ qzstate, const int* __restrict__ mask,
                             u16* __restrict__ qzb){
  int t = threadIdx.x; int lane = t & 63; int w = t >> 6;
  int row = blockIdx.x*4 + w;
  float v = qzstate[(size_t)row*64 + lane];
  float mx = wred_max(v);
  float e = __expf(v - mx);
  float s = wred_sum(e);
  float mk = (mask[row] != 0) ? 1.f : 0.f;
  qzb[(size_t)row*64 + lane] = f2b(e / s * mk);
}

// ---- kT: qzTb[z][a][i] = qzb[z][i][a] (64x64 LDS tiles) ----
__global__ void kT_qzT(const u16* __restrict__ qzb, u16* __restrict__ qzTb){
  int bid = blockIdx.x;                 // z*8 + itile
  int itile = bid & 7, z = bid >> 3; int i0 = itile*64;
  __shared__ u16 lds[64][66];
  int t = threadIdx.x;
  #pragma unroll
  for(int m=0;m<16;m++){
    int e = t + 256*m; int row = e>>6, a = e&63;
    lds[a][row] = qzb[((size_t)z*LL + i0 + row)*64 + a];
  }
  __syncthreads();
  #pragma unroll
  for(int p=0;p<16;p++){
    int a = (t>>6) + 4*p; int i = t&63;
    qzTb[((size_t)z*64 + a)*LL + i0 + i] = lds[a][i];
  }
}

// ---- k2: t1[z,c] = qz @ T_c  (M=512,K=64,N=64) -> bf16 ----
__global__ void k2_t1(const u16* __restrict__ qzb, const u16* __restrict__ T4t,
                      u16* __restrict__ t1b){
  int bid = blockIdx.x;                 // (z*8+c)*8 + itile
  int itile = bid&7, c = (bid>>3)&7, z = bid>>6;
  int t = threadIdx.x, lane = t&63, w = t>>6;
  int l15 = lane&15, lhi = lane>>4;
  int r0 = itile*64 + w*16;
  const u16* Ar = qzb + ((size_t)z*LL + r0 + l15)*64 + lhi*8;
  bf16x8 a0 = ldb8(Ar), a1 = ldb8(Ar + 32);
  #pragma unroll
  for(int nt=0;nt<4;nt++){
    const u16* Br = T4t + (size_t)c*4096 + (nt*16 + l15)*64 + lhi*8;
    f32x4 acc = {0.f,0.f,0.f,0.f};
    acc = MFMA(a0, ldb8(Br), acc);
    acc = MFMA(a1, ldb8(Br+32), acc);
    #pragma unroll
    for(int j=0;j<4;j++)
      t1b[((size_t)(z*8+c)*LL + r0 + lhi*4 + j)*64 + nt*16 + l15] = f2b(acc[j]);
  }
}

// ---- k4: P2 = rowsoftmax(qz @ G^T) -> bf16 ----
__global__ void k4_p2(const u16* __restrict__ qzb, const float* __restrict__ gw,
                      u16* __restrict__ P2b){
  int t = threadIdx.x; int lane = t & 63; int w = t >> 6;
  int row = blockIdx.x*4 + w;
  __shared__ float Gs[64][65];
  #pragma unroll
  for(int m=0;m<16;m++){ int e = t + 256*m; int j = e>>6, a = e&63; Gs[j][a] = gw[(size_t)j*64 + a]; }
  __syncthreads();
  float qv = b2f(qzb[(size_t)row*64 + lane]);
  float s = 0.f;
  for(int a=0;a<64;a++){
    float q = __shfl(qv, a, 64);
    s += q * Gs[lane][a];
  }
  float mx = wred_max(s);
  float e = __expf(s - mx);
  float sum = wred_sum(e);
  P2b[(size_t)row*64 + lane] = f2b(e / sum);
}

// ---- k3a: F1 = t1 @ qz^T, mask+diag, row softmax -> P bf16 + stats ----
__global__ void k3a(const u16* __restrict__ t1b, const u16* __restrict__ qzb,
                    const int* __restrict__ mask, u16* __restrict__ P,
                    float* __restrict__ rmS, float* __restrict__ invS, int zbase){
  int bid = blockIdx.x;                 // (zg*8+c)*32 + itile
  int itile = bid & 31, c = (bid>>5)&7, zg = bid>>8; int z = zbase + zg;
  int t = threadIdx.x, lane = t&63, w = t>>6;
  int l15 = lane&15, lhi = lane>>4;
  int i0 = itile*16;
  int wcol0 = w*128;
  const u16* t1r = t1b + ((size_t)((z*8+c)*LL) + i0 + l15)*64 + lhi*8;
  bf16x8 a0 = ldb8(t1r), a1 = ldb8(t1r + 32);
  f32x4 f[8];
  #pragma unroll
  for(int t16=0;t16<8;t16++){
    const u16* qr = qzb + ((size_t)z*LL + wcol0 + t16*16 + l15)*64 + lhi*8;
    f32x4 acc = {0.f,0.f,0.f,0.f};
    acc = MFMA(a0, ldb8(qr), acc);
    acc = MFMA(a1, ldb8(qr+32), acc);
    f[t16] = acc;
  }
  int mr[4];
  #pragma unroll
  for(int j=0;j<4;j++) mr[j] = mask[z*LL + i0 + lhi*4 + j];
  float pm[4] = {-3e38f,-3e38f,-3e38f,-3e38f};
  #pragma unroll
  for(int t16=0;t16<8;t16++){
    int jcol = wcol0 + t16*16 + l15;
    int cvv = mask[z*LL + jcol];
    #pragma unroll
    for(int j=0;j<4;j++){
      int irow = i0 + lhi*4 + j;
      float v = f[t16][j];
      v = (mr[j] && cvv) ? v - ((irow==jcol)?BIGV:0.f) : NEGV;
      f[t16][j] = v;
      pm[j] = fmaxf(pm[j], v);
    }
  }
  __shared__ float red1[4][16], red2[4][16];
  #pragma unroll
  for(int j=0;j<4;j++) pm[j] = g16_max(pm[j]);
  if(l15==0){
    #pragma unroll
    for(int j=0;j<4;j++) red1[w][lhi*4+j] = pm[j];
  }
  __syncthreads();
  float rm[4];
  #pragma unroll
  for(int j=0;j<4;j++){
    int r = lhi*4+j;
    rm[j] = fmaxf(fmaxf(red1[0][r],red1[1][r]), fmaxf(red1[2][r],red1[3][r]));
  }
  float es[4] = {0.f,0.f,0.f,0.f};
  #pragma unroll
  for(int t16=0;t16<8;t16++)
    #pragma unroll
    for(int j=0;j<4;j++){
      float e = __expf(f[t16][j] - rm[j]);
      f[t16][j] = e; es[j] += e;
    }
  #pragma unroll
  for(int j=0;j<4;j++) es[j] = g16_sum(es[j]);
  if(l15==0){
    #pragma unroll
    for(int j=0;j<4;j++) red2[w][lhi*4+j] = es[j];
  }
  __syncthreads();
  float iv[4];
  #pragma unroll
  for(int j=0;j<4;j++){
    int r = lhi*4+j;
    iv[j] = 1.f / (red2[0][r]+red2[1][r]+red2[2][r]+red2[3][r]);
  }
  if(w==0 && l15==0){
    #pragma unroll
    for(int j=0;j<4;j++){
      size_t si = (size_t)(z*8+c)*LL + i0 + lhi*4 + j;
      rmS[si] = rm[j]; invS[si] = iv[j];
    }
  }
  u16* Pb = P + ((size_t)(zg*8+c)*LL + i0)*LL;
  #pragma unroll
  for(int t16=0;t16<8;t16++)
    #pragma unroll
    for(int j=0;j<4;j++)
      Pb[(size_t)(lhi*4+j)*LL + wcol0 + t16*16 + l15] = f2b(f[t16][j]*iv[j]);
}

// ---- k3b: F1^T = qz @ t1^T with saved stats -> PT bf16 ----
__global__ void k3b(const u16* __restrict__ t1b, const u16* __restrict__ qzb,
                    const int* __restrict__ mask, const float* __restrict__ rmS,
                    const float* __restrict__ invS, u16* __restrict__ PT, int zbase){
  int bid = blockIdx.x;                 // (zg*8+c)*32 + jtile
  int jtile = bid & 31, c = (bid>>5)&7, zg = bid>>8; int z = zbase + zg;
  int t = threadIdx.x, lane = t&63, w = t>>6;
  int l15 = lane&15, lhi = lane>>4;
  int j0 = jtile*16;
  int wcol0 = w*128;
  const u16* qr = qzb + ((size_t)z*LL + j0 + l15)*64 + lhi*8;
  bf16x8 a0 = ldb8(qr), a1 = ldb8(qr + 32);
  f32x4 f[8];
  #pragma unroll
  for(int t16=0;t16<8;t16++){
    const u16* t1r = t1b + ((size_t)((z*8+c)*LL) + wcol0 + t16*16 + l15)*64 + lhi*8;
    f32x4 acc = {0.f,0.f,0.f,0.f};
    acc = MFMA(a0, ldb8(t1r), acc);
    acc = MFMA(a1, ldb8(t1r+32), acc);
    f[t16] = acc;
  }
  int mr[4];
  #pragma unroll
  for(int j=0;j<4;j++) mr[j] = mask[z*LL + j0 + lhi*4 + j];
  #pragma unroll
  for(int t16=0;t16<8;t16++){
    int icol = wcol0 + t16*16 + l15;
    int miv = mask[z*LL + icol];
    float rm = rmS[(size_t)(z*8+c)*LL + icol];
    float iv = invS[(size_t)(z*8+c)*LL + icol];
    #pragma unroll
    for(int j=0;j<4;j++){
      int jrow = j0 + lhi*4 + j;
      float v = f[t16][j];
      v = (mr[j] && miv) ? v - ((jrow==icol)?BIGV:0.f) : NEGV;
      float pt = __expf(v - rm) * iv;
      PT[((size_t)(zg*8+c)*LL + jrow)*LL + icol] = f2b(pt);
    }
  }
}

// ---- k5a: out[z][m][c*64+n] = A(512x512) @ qzT-B (N=64,K=512) ----
__global__ void k5a(const u16* __restrict__ A, const u16* __restrict__ qzTb,
                    u16* __restrict__ outF, int zbase){
  int bid = blockIdx.x;                 // (zg*8+c)*8 + mtile
  int mtile = bid&7, c = (bid>>3)&7, zg = bid>>6; int z = zbase + zg;
  int t = threadIdx.x, lane = t&63, w = t>>6;
  int l15 = lane&15, lhi = lane>>4;
  int r0 = mtile*64 + w*16;
  const u16* Ab = A + ((size_t)(zg*8+c)*LL + r0 + l15)*LL + lhi*8;
  const u16* Qt = qzTb + (size_t)z*64*LL + lhi*8;
  f32x4 acc[4];
  #pragma unroll
  for(int nt=0;nt<4;nt++) acc[nt] = (f32x4){0.f,0.f,0.f,0.f};
  for(int ks=0;ks<16;ks++){
    bf16x8 a = ldb8(Ab + ks*32);
    #pragma unroll
    for(int nt=0;nt<4;nt++){
      bf16x8 b = ldb8(Qt + (size_t)(nt*16 + l15)*LL + ks*32);
      acc[nt] = MFMA(a, b, acc[nt]);
    }
  }
  #pragma unroll
  for(int nt=0;nt<4;nt++)
    #pragma unroll
    for(int j=0;j<4;j++)
      outF[((size_t)z*LL + r0 + lhi*4 + j)*512 + c*64 + nt*16 + l15] = f2b(acc[nt][j]);
}

// ---- k5c: new_qz = (unary + miF@T2t + mjF@T3t + P2@Gt) * m1 ----
__global__ void k5c(const u16* __restrict__ miF, const u16* __restrict__ mjF,
                    const u16* __restrict__ P2b, const u16* __restrict__ T2t,
                    const u16* __restrict__ T3t, const u16* __restrict__ Gt,
                    const float* __restrict__ unary, const int* __restrict__ mask,
                    float* __restrict__ outq){
  int bid = blockIdx.x;                 // z*32 + itile
  int itile = bid & 31, z = bid >> 5;
  int t = threadIdx.x, lane = t&63, w = t>>6;
  int l15 = lane&15, lhi = lane>>4;
  int i0 = itile*16;
  int n0 = w*16;
  f32x4 acc = {0.f,0.f,0.f,0.f};
  {
    const u16* Ar = miF + ((size_t)z*LL + i0 + l15)*512 + lhi*8;
    const u16* Br = T2t + (size_t)(n0 + l15)*512 + lhi*8;
    for(int ks=0;ks<16;ks++) acc = MFMA(ldb8(Ar + ks*32), ldb8(Br + ks*32), acc);
  }
  {
    const u16* Ar = mjF + ((size_t)z*LL + i0 + l15)*512 + lhi*8;
    const u16* Br = T3t + (size_t)(n0 + l15)*512 + lhi*8;
    for(int ks=0;ks<16;ks++) acc = MFMA(ldb8(Ar + ks*32), ldb8(Br + ks*32), acc);
  }
  {
    const u16* Ar = P2b + ((size_t)z*LL + i0 + l15)*64 + lhi*8;
    const u16* Br = Gt + (size_t)(n0 + l15)*64 + lhi*8;
    acc = MFMA(ldb8(Ar), ldb8(Br), acc);
    acc = MFMA(ldb8(Ar+32), ldb8(Br+32), acc);
  }
  #pragma unroll
  for(int j=0;j<4;j++){
    int row = i0 + lhi*4 + j;
    float mk = (mask[z*LL + row] != 0) ? 1.f : 0.f;
    size_t idx = ((size_t)z*LL + row)*64 + n0 + l15;
    outq[idx] = (unary[idx] + acc[j]) * mk;
  }
}

extern "C" void kernel_launch(void* const* d_in, const int* in_sizes, int n_in,
                              void* d_out, int out_size, void* d_ws, size_t ws_size,
                              hipStream_t stream) {
  const float* x       = (const float*)d_in[0];
  const int*   mask    = (const int*)d_in[1];
  const float* ternary = (const float*)d_in[2];
  const float* gw      = (const float*)d_in[3];
  float* out = (float*)d_out;

  const size_t NE = (size_t)BB*LL*64;          // 262144
  char* p = (char*)d_ws;
  char* base = p;
  auto alloc = [&](size_t bytes)->void*{
    void* r = (void*)p; p += (bytes + 255) & ~(size_t)255; return r;
  };
  float* unary   = (float*)alloc(NE*4);
  float* qzstate = (float*)alloc(NE*4);
  u16*   qzb     = (u16*)alloc(NE*2);
  u16*   qzTb    = (u16*)alloc(NE*2);
  u16*   t1b     = (u16*)alloc((size_t)BB*HH*LL*64*2);
  u16*   P2b     = (u16*)alloc(NE*2);
  u16*   miF     = (u16*)alloc((size_t)BB*LL*512*2);
  u16*   mjF     = (u16*)alloc((size_t)BB*LL*512*2);
  float* rmS     = (float*)alloc((size_t)64*LL*4);
  float* invS    = (float*)alloc((size_t)64*LL*4);
  u16*   T4t     = (u16*)alloc(32768*2);
  u16*   T2t     = (u16*)alloc(32768*2);
  u16*   T3t     = (u16*)alloc(32768*2);
  u16*   Gt      = (u16*)alloc(4096*2);

  const size_t PZB = (size_t)HH*LL*LL*2;       // 4 MiB per z per tensor
  size_t used = (size_t)(p - base);
  long long avail = (long long)ws_size - (long long)used;
  int g = (int)(avail / (long long)(2*PZB + 512));
  if(g > BB) g = BB; if(g < 1) g = 1;
  u16* P  = (u16*)alloc((size_t)g*PZB);
  u16* PT = (u16*)alloc((size_t)g*PZB);

  kp_prep<<<128, 256, 0, stream>>>(ternary, gw, T4t, T2t, T3t, Gt);
  k0_init<<<(int)(NE/256), 256, 0, stream>>>(x, mask, unary, qzstate);
  for(int it=0; it<4; ++it){
    k1_softmax64<<<(BB*LL)/4, 256, 0, stream>>>(qzstate, mask, qzb);
    kT_qzT<<<BB*8, 256, 0, stream>>>(qzb, qzTb);
    k2_t1<<<BB*HH*8, 256, 0, stream>>>(qzb, T4t, t1b);
    k4_p2<<<(BB*LL)/4, 256, 0, stream>>>(qzb, gw, P2b);
    for(int zbase=0; zbase<BB; zbase+=g){
      int gg = (BB - zbase < g) ? (BB - zbase) : g;
      k3a<<<gg*HH*32, 256, 0, stream>>>(t1b, qzb, mask, P, rmS, invS, zbase);
      k3b<<<gg*HH*32, 256, 0, stream>>>(t1b, qzb, mask, rmS, invS, PT, zbase);
      k5a<<<gg*HH*8, 256, 0, stream>>>(P,  qzTb, miF, zbase);
      k5a<<<gg*HH*8, 256, 0, stream>>>(PT, qzTb, mjF, zbase);
    }
    float* outq = (it==3) ? out : qzstate;
    k5c<<<BB*32, 256, 0, stream>>>(miF, mjF, P2b, T2t, T3t, Gt, unary, mask, outq);
  }
}

// Round 4
// 432.173 us; speedup vs baseline: 23.1321x; 1.1112x over previous
//
#include <hip/hip_runtime.h>

#define BB 8
#define LL 512
#define HH 8
#define NEGV (-1e9f)
#define BIGV (1e9f)

typedef unsigned short u16;
typedef __attribute__((ext_vector_type(8))) short bf16x8;
typedef __attribute__((ext_vector_type(4))) short s16x4;
typedef __attribute__((ext_vector_type(4))) float f32x4;

#define MFMA(a,b,c) __builtin_amdgcn_mfma_f32_16x16x32_bf16(a,b,c,0,0,0)

__device__ __forceinline__ u16 f2b(float f){
  unsigned u = __float_as_uint(f);
  u = (u + 0x7fffu + ((u>>16)&1u)) >> 16;
  return (u16)u;
}
__device__ __forceinline__ bf16x8 ldb8(const u16* p){ return *(const bf16x8*)p; }

__device__ __forceinline__ float wred_max(float v){
  #pragma unroll
  for(int off=32;off>0;off>>=1) v = fmaxf(v, __shfl_xor(v, off, 64));
  return v;
}
__device__ __forceinline__ float wred_sum(float v){
  #pragma unroll
  for(int off=32;off>0;off>>=1) v += __shfl_xor(v, off, 64);
  return v;
}
__device__ __forceinline__ float g16_sum(float v){
  v += __shfl_xor(v,1,64); v += __shfl_xor(v,2,64);
  v += __shfl_xor(v,4,64); v += __shfl_xor(v,8,64);
  return v;
}

// ---- prep: bf16 ternary tables ----
// T4t[c][b][a], T2t[a][c*64+b], T3t[b][c*64+a], Gt[a][j], Gt2[j][a]
__global__ void kp_prep(const float* __restrict__ T, const float* __restrict__ gw,
                        u16* __restrict__ T4t, u16* __restrict__ T2t,
                        u16* __restrict__ T3t, u16* __restrict__ Gt, u16* __restrict__ Gt2){
  int idx = blockIdx.x*256 + threadIdx.x;   // < 32768
  { int c=idx>>12, b=(idx>>6)&63, a=idx&63; T4t[idx] = f2b(T[(a*64+b)*8+c]); }
  { int a=idx>>9,  c=(idx>>6)&7,  b=idx&63; T2t[idx] = f2b(T[(a*64+b)*8+c]); }
  { int b=idx>>9,  c=(idx>>6)&7,  a=idx&63; T3t[idx] = f2b(T[(a*64+b)*8+c]); }
  if(idx < 4096){
    int a=idx>>6, j=idx&63;
    Gt[idx]  = f2b(gw[j*64+a]);   // Gt[a][j]
    Gt2[idx] = f2b(gw[idx]);      // Gt2[j][a] (gw is already [j][a])
  }
}

// ---- k0: unary = (x + pe) * m1 ; qzstate = unary ----
__global__ void k0_init(const float* __restrict__ x, const int* __restrict__ mask,
                        float* __restrict__ unary, float* __restrict__ qzstate){
  int idx = blockIdx.x*256 + threadIdx.x;
  int d = idx & 63; int row = idx >> 6;
  int pos = row & (LL-1);
  int k2 = d & ~1;
  float div = __expf(-(float)k2 * 0.14391156962f);  // ln(10000)/64
  float arg = (float)pos * div;
  float pe = (d & 1) ? cosf(arg) : sinf(arg);
  float mk = (mask[row] != 0) ? 1.f : 0.f;
  float u = (x[idx] + pe) * mk;
  unary[idx] = u; qzstate[idx] = u;
}

// ---- kA: fused softmax64 -> qzb, qzT transpose -> qzTb, P2 softmax -> P2b ----
__global__ __launch_bounds__(256) void kA(const float* __restrict__ qzstate,
      const int* __restrict__ mask, const u16* __restrict__ Gt2,
      u16* __restrict__ qzb, u16* __restrict__ qzTb, u16* __restrict__ P2b){
  __shared__ u16 qlds[64][72];
  int bid = blockIdx.x; int itile = bid & 7, z = bid >> 3;
  int t = threadIdx.x, lane = t&63, w = t>>6;
  int l15 = lane&15, lhi = lane>>4;
  int rbase_g = z*LL + itile*64;
  // phase 1: row softmax (exact max, magnitudes unbounded here)
  for(int p=0;p<16;p++){
    int rl = w*16 + p;
    int rg = rbase_g + rl;
    float v = qzstate[(size_t)rg*64 + lane];
    float mx = wred_max(v);
    float e = __expf(v - mx);
    float s = wred_sum(e);
    float mk = (mask[rg] != 0) ? 1.f : 0.f;
    u16 q = f2b(e/s*mk);
    qzb[(size_t)rg*64 + lane] = q;
    qlds[rl][lane] = q;
  }
  __syncthreads();
  // phase 2: transposed copy -> qzTb[z][a][i]
  #pragma unroll
  for(int p=0;p<16;p++){
    int a = w + 4*p; int i = lane;
    qzTb[((size_t)z*64 + a)*LL + itile*64 + i] = qlds[i][a];
  }
  // phase 3: P2 = rowsoftmax(qz @ gw^T), logits bounded ~|gw| -> fixed-M exp
  f32x4 f[4];
  {
    const u16* Ar = &qlds[w*16 + l15][lhi*8];
    bf16x8 a0 = ldb8(Ar), a1 = ldb8(Ar+32);
    #pragma unroll
    for(int ct=0;ct<4;ct++){
      const u16* Br = Gt2 + (size_t)(ct*16 + l15)*64 + lhi*8;
      f32x4 acc = {0.f,0.f,0.f,0.f};
      acc = MFMA(a0, ldb8(Br), acc);
      acc = MFMA(a1, ldb8(Br+32), acc);
      f[ct] = acc;
    }
  }
  #pragma unroll
  for(int jj=0;jj<4;jj++){
    float ps = 0.f;
    #pragma unroll
    for(int ct=0;ct<4;ct++){ float e = __expf(f[ct][jj]); f[ct][jj] = e; ps += e; }
    float s = g16_sum(ps);
    float iv = 1.f/s;
    int rg = rbase_g + w*16 + lhi*4 + jj;
    #pragma unroll
    for(int ct=0;ct<4;ct++)
      P2b[(size_t)rg*64 + ct*16 + l15] = f2b(f[ct][jj]*iv);
  }
}

// ---- k2: t1[z,c] = qz @ T_c  (M=512,K=64,N=64) -> bf16 ----
__global__ void k2_t1(const u16* __restrict__ qzb, const u16* __restrict__ T4t,
                      u16* __restrict__ t1b){
  int bid = blockIdx.x;                 // (z*8+c)*8 + itile
  int itile = bid&7, c = (bid>>3)&7, z = bid>>6;
  int t = threadIdx.x, lane = t&63, w = t>>6;
  int l15 = lane&15, lhi = lane>>4;
  int r0 = itile*64 + w*16;
  const u16* Ar = qzb + ((size_t)z*LL + r0 + l15)*64 + lhi*8;
  bf16x8 a0 = ldb8(Ar), a1 = ldb8(Ar + 32);
  #pragma unroll
  for(int nt=0;nt<4;nt++){
    const u16* Br = T4t + (size_t)c*4096 + (nt*16 + l15)*64 + lhi*8;
    f32x4 acc = {0.f,0.f,0.f,0.f};
    acc = MFMA(a0, ldb8(Br), acc);
    acc = MFMA(a1, ldb8(Br+32), acc);
    #pragma unroll
    for(int j=0;j<4;j++)
      t1b[((size_t)(z*8+c)*LL + r0 + lhi*4 + j)*64 + nt*16 + l15] = f2b(acc[j]);
  }
}

// ---- kF: fused S -> softmax(fixed M) -> P(LDS) -> mi(out) + mj(acc, 4 quarters) ----
__global__ __launch_bounds__(512) void kF(const u16* __restrict__ t1b, const u16* __restrict__ qzb,
        const u16* __restrict__ qzTb, const int* __restrict__ mask,
        u16* __restrict__ miF, u16* __restrict__ mjF4){
  extern __shared__ char smem[];
  u16* Pp  = (u16*)smem;                        // [64][520]
  u16* PpT = Pp + 64*520;                       // [512][72]
  float* red = (float*)(PpT + (size_t)512*72);  // [64][8]
  int bid = blockIdx.x;                         // (z*8+c)*4 + iq
  int iq = bid & 3, c = (bid>>2)&7, z = bid>>5;
  int t = threadIdx.x, lane = t&63, w = t>>6;
  int l15 = lane&15, lhi = lane>>4;
  int zc = z*8 + c;
  int I0 = iq*128;
  f32x4 mj[4][4];
  #pragma unroll
  for(int jt=0;jt<4;jt++)
    #pragma unroll
    for(int bt=0;bt<4;bt++) mj[jt][bt] = (f32x4){0.f,0.f,0.f,0.f};

  for(int ip=0; ip<2; ip++){
    int i0g = I0 + ip*64;
    // ---- S panel: rows i0g..+64, cols w*64..+64 ----
    f32x4 S[4][4];
    #pragma unroll
    for(int rt=0;rt<4;rt++)
      #pragma unroll
      for(int ct=0;ct<4;ct++) S[rt][ct] = (f32x4){0.f,0.f,0.f,0.f};
    bf16x8 a0[4], a1[4];
    #pragma unroll
    for(int rt=0;rt<4;rt++){
      const u16* Ar = t1b + ((size_t)zc*LL + i0g + rt*16 + l15)*64 + lhi*8;
      a0[rt] = ldb8(Ar); a1[rt] = ldb8(Ar+32);
    }
    #pragma unroll
    for(int ct=0;ct<4;ct++){
      const u16* Br = qzb + ((size_t)z*LL + w*64 + ct*16 + l15)*64 + lhi*8;
      bf16x8 b0 = ldb8(Br), b1 = ldb8(Br+32);
      #pragma unroll
      for(int rt=0;rt<4;rt++){
        S[rt][ct] = MFMA(a0[rt], b0, S[rt][ct]);
        S[rt][ct] = MFMA(a1[rt], b1, S[rt][ct]);
      }
    }
    // ---- mask + diag + exp (fixed M: |S| <= max|T| ~ 5, no overflow) ----
    int cv[4];
    #pragma unroll
    for(int ct=0;ct<4;ct++) cv[ct] = mask[z*LL + w*64 + ct*16 + l15];
    #pragma unroll
    for(int rt=0;rt<4;rt++){
      #pragma unroll
      for(int jj=0;jj<4;jj++){
        int irow = i0g + rt*16 + lhi*4 + jj;
        int mr = mask[z*LL + irow];
        float ps = 0.f;
        #pragma unroll
        for(int ct=0;ct<4;ct++){
          int jcol = w*64 + ct*16 + l15;
          float v = S[rt][ct][jj];
          v = (mr && cv[ct]) ? v - ((irow==jcol)?BIGV:0.f) : NEGV;
          float e = __expf(v);
          S[rt][ct][jj] = e; ps += e;
        }
        ps = g16_sum(ps);
        if(l15==0) red[(rt*16 + lhi*4 + jj)*8 + w] = ps;
      }
    }
    __syncthreads();
    // ---- normalize + write Pp (row-major) and PpT (transposed, packed x4) ----
    #pragma unroll
    for(int rt=0;rt<4;rt++){
      float iv[4];
      #pragma unroll
      for(int jj=0;jj<4;jj++){
        int rl = rt*16 + lhi*4 + jj;
        f32x4 s0 = *(f32x4*)&red[rl*8];
        f32x4 s1 = *(f32x4*)&red[rl*8+4];
        float s = s0[0]+s0[1]+s0[2]+s0[3]+s1[0]+s1[1]+s1[2]+s1[3];
        iv[jj] = s > 0.f ? 1.f/s : 0.f;
      }
      #pragma unroll
      for(int ct=0;ct<4;ct++){
        int jcol = w*64 + ct*16 + l15;
        u16 p4[4];
        #pragma unroll
        for(int jj=0;jj<4;jj++){
          u16 pb = f2b(S[rt][ct][jj]*iv[jj]);
          Pp[(rt*16 + lhi*4 + jj)*520 + jcol] = pb;
          p4[jj] = pb;
        }
        s16x4 v4 = { (short)p4[0], (short)p4[1], (short)p4[2], (short)p4[3] };
        *(s16x4*)&PpT[(size_t)jcol*72 + rt*16 + lhi*4] = v4;
      }
    }
    __syncthreads();
    // ---- mi: rows (w>>1)*16, cols (w&1)*32, K=512 from Pp ----
    {
      int rb = (w>>1)*16;
      int b0c = (w&1)*32;
      f32x4 m0 = {0.f,0.f,0.f,0.f}, m1 = {0.f,0.f,0.f,0.f};
      const u16* Bb  = qzTb + ((size_t)z*64 + b0c + l15)*LL + lhi*8;
      const u16* Bb2 = Bb + (size_t)16*LL;
      for(int ks=0;ks<16;ks++){
        bf16x8 a = ldb8(Pp + (rb + l15)*520 + ks*32 + lhi*8);
        m0 = MFMA(a, ldb8(Bb  + ks*32), m0);
        m1 = MFMA(a, ldb8(Bb2 + ks*32), m1);
      }
      #pragma unroll
      for(int jj=0;jj<4;jj++){
        size_t row = (size_t)z*LL + i0g + rb + lhi*4 + jj;
        miF[row*512 + c*64 + b0c + l15]      = f2b(m0[jj]);
        miF[row*512 + c*64 + b0c + 16 + l15] = f2b(m1[jj]);
      }
    }
    // ---- mj accumulate: wave owns j-slice w*64..+64, K=64 (this panel) from PpT ----
    #pragma unroll
    for(int ks=0;ks<2;ks++){
      bf16x8 av[4];
      #pragma unroll
      for(int jt=0;jt<4;jt++)
        av[jt] = ldb8(PpT + (size_t)(w*64 + jt*16 + l15)*72 + ks*32 + lhi*8);
      #pragma unroll
      for(int bt=0;bt<4;bt++){
        bf16x8 b = ldb8(qzTb + ((size_t)z*64 + bt*16 + l15)*LL + i0g + ks*32 + lhi*8);
        #pragma unroll
        for(int jt=0;jt<4;jt++) mj[jt][bt] = MFMA(av[jt], b, mj[jt][bt]);
      }
    }
  }
  // ---- dump mj via LDS stage (reuse Pp region) for coalesced stores ----
  __syncthreads();
  u16* stg = Pp;  // 512*64 u16 = 32768 <= 64*520
  #pragma unroll
  for(int jt=0;jt<4;jt++)
    #pragma unroll
    for(int bt=0;bt<4;bt++)
      #pragma unroll
      for(int jj=0;jj<4;jj++)
        stg[w*4096 + (jt*16 + lhi*4 + jj)*64 + bt*16 + l15] = f2b(mj[jt][bt][jj]);
  __syncthreads();
  #pragma unroll
  for(int q=0;q<8;q++){
    int e = t + 512*q;
    int j = e >> 3, bblk = e & 7;
    size_t dst = (((size_t)(iq*BB + z)*LL + j)*512) + c*64 + bblk*8;
    *(bf16x8*)&mjF4[dst] = *(const bf16x8*)&stg[e*8];
  }
}

// ---- k5c: new_qz = (unary + miF@T2t + sum_q mjF4[q]@T3t + P2@Gt) * m1 ----
__global__ __launch_bounds__(256) void k5c(const u16* __restrict__ miF, const u16* __restrict__ mjF4,
        const u16* __restrict__ P2b, const u16* __restrict__ T2t, const u16* __restrict__ T3t,
        const u16* __restrict__ Gt, const float* __restrict__ unary, const int* __restrict__ mask,
        float* __restrict__ outq){
  int bid = blockIdx.x; int itile = bid & 31, z = bid >> 5;
  int t = threadIdx.x, lane = t&63, w = t>>6;
  int l15 = lane&15, lhi = lane>>4;
  int i0 = itile*16;
  int n0 = w*16;
  const size_t MJQ = (size_t)BB*LL*512;
  f32x4 acc0 = {0.f,0.f,0.f,0.f}, acc1 = {0.f,0.f,0.f,0.f}, acc2 = {0.f,0.f,0.f,0.f};
  const u16* Ami  = miF  + ((size_t)z*LL + i0 + l15)*512 + lhi*8;
  const u16* Amj0 = mjF4 + ((size_t)z*LL + i0 + l15)*512 + lhi*8;
  const u16* Amj1 = Amj0 + MJQ;
  const u16* Amj2 = Amj1 + MJQ;
  const u16* Amj3 = Amj2 + MJQ;
  const u16* Bi = T2t + (size_t)(n0 + l15)*512 + lhi*8;
  const u16* Bj = T3t + (size_t)(n0 + l15)*512 + lhi*8;
  for(int ks=0;ks<16;ks++){
    bf16x8 bi = ldb8(Bi + ks*32);
    bf16x8 bj = ldb8(Bj + ks*32);
    acc0 = MFMA(ldb8(Ami  + ks*32), bi, acc0);
    acc1 = MFMA(ldb8(Amj0 + ks*32), bj, acc1);
    acc2 = MFMA(ldb8(Amj1 + ks*32), bj, acc2);
    acc1 = MFMA(ldb8(Amj2 + ks*32), bj, acc1);
    acc2 = MFMA(ldb8(Amj3 + ks*32), bj, acc2);
  }
  {
    const u16* Ar = P2b + ((size_t)z*LL + i0 + l15)*64 + lhi*8;
    const u16* Br = Gt + (size_t)(n0 + l15)*64 + lhi*8;
    acc0 = MFMA(ldb8(Ar), ldb8(Br), acc0);
    acc0 = MFMA(ldb8(Ar+32), ldb8(Br+32), acc0);
  }
  #pragma unroll
  for(int jj=0;jj<4;jj++){
    int row = i0 + lhi*4 + jj;
    float mk = (mask[z*LL + row] != 0) ? 1.f : 0.f;
    size_t idx = ((size_t)z*LL + row)*64 + n0 + l15;
    outq[idx] = (unary[idx] + acc0[jj] + acc1[jj] + acc2[jj]) * mk;
  }
}

extern "C" void kernel_launch(void* const* d_in, const int* in_sizes, int n_in,
                              void* d_out, int out_size, void* d_ws, size_t ws_size,
                              hipStream_t stream) {
  const float* x       = (const float*)d_in[0];
  const int*   mask    = (const int*)d_in[1];
  const float* ternary = (const float*)d_in[2];
  const float* gw      = (const float*)d_in[3];
  float* out = (float*)d_out;

  const size_t NE = (size_t)BB*LL*64;          // 262144
  char* p = (char*)d_ws;
  auto alloc = [&](size_t bytes)->void*{
    void* r = (void*)p; p += (bytes + 255) & ~(size_t)255; return r;
  };
  float* unary   = (float*)alloc(NE*4);
  float* qzstate = (float*)alloc(NE*4);
  u16*   qzb     = (u16*)alloc(NE*2);
  u16*   qzTb    = (u16*)alloc(NE*2);
  u16*   t1b     = (u16*)alloc((size_t)BB*HH*LL*64*2);   // 4.2 MB
  u16*   P2b     = (u16*)alloc(NE*2);
  u16*   miF     = (u16*)alloc((size_t)BB*LL*512*2);     // 4.2 MB
  u16*   mjF4    = (u16*)alloc((size_t)4*BB*LL*512*2);   // 16.8 MB
  u16*   T4t     = (u16*)alloc(32768*2);
  u16*   T2t     = (u16*)alloc(32768*2);
  u16*   T3t     = (u16*)alloc(32768*2);
  u16*   Gt      = (u16*)alloc(4096*2);
  u16*   Gt2     = (u16*)alloc(4096*2);

  const int KF_LDS = 64*520*2 + 512*72*2 + 64*8*4;   // 142336
  hipFuncSetAttribute(reinterpret_cast<const void*>(kF),
                      hipFuncAttributeMaxDynamicSharedMemorySize, KF_LDS);

  kp_prep<<<128, 256, 0, stream>>>(ternary, gw, T4t, T2t, T3t, Gt, Gt2);
  k0_init<<<(int)(NE/256), 256, 0, stream>>>(x, mask, unary, qzstate);
  for(int it=0; it<4; ++it){
    kA<<<BB*8, 256, 0, stream>>>(qzstate, mask, Gt2, qzb, qzTb, P2b);
    k2_t1<<<BB*HH*8, 256, 0, stream>>>(qzb, T4t, t1b);
    kF<<<BB*HH*4, 512, KF_LDS, stream>>>(t1b, qzb, qzTb, mask, miF, mjF4);
    float* outq = (it==3) ? out : qzstate;
    k5c<<<BB*32, 256, 0, stream>>>(miF, mjF4, P2b, T2t, T3t, Gt, unary, mask, outq);
  }
}

// Round 5
// 419.756 us; speedup vs baseline: 23.8164x; 1.0296x over previous
//
#include <hip/hip_runtime.h>

#define BB 8
#define LL 512
#define HH 8
#define BIGV (1e9f)

typedef unsigned short u16;
typedef __attribute__((ext_vector_type(8))) short bf16x8;
typedef __attribute__((ext_vector_type(4))) short s16x4;
typedef __attribute__((ext_vector_type(4))) float f32x4;

#define MFMA(a,b,c) __builtin_amdgcn_mfma_f32_16x16x32_bf16(a,b,c,0,0,0)

__device__ __forceinline__ u16 f2b(float f){
  unsigned u = __float_as_uint(f);
  u = (u + 0x7fffu + ((u>>16)&1u)) >> 16;
  return (u16)u;
}
__device__ __forceinline__ float b2f(u16 s){ return __uint_as_float(((unsigned)s)<<16); }
__device__ __forceinline__ bf16x8 ldb8(const u16* p){ return *(const bf16x8*)p; }

__device__ __forceinline__ float wred_max(float v){
  #pragma unroll
  for(int off=32;off>0;off>>=1) v = fmaxf(v, __shfl_xor(v, off, 64));
  return v;
}
__device__ __forceinline__ float wred_sum(float v){
  #pragma unroll
  for(int off=32;off>0;off>>=1) v += __shfl_xor(v, off, 64);
  return v;
}
__device__ __forceinline__ float g16_sum(float v){
  v += __shfl_xor(v,1,64); v += __shfl_xor(v,2,64);
  v += __shfl_xor(v,4,64); v += __shfl_xor(v,8,64);
  return v;
}

// ---- tables: T4t[c][b][a], Tt2[c][a][b], Gt[a][j], Gt2[j][a] ----
__global__ void kp_prep(const float* __restrict__ T, const float* __restrict__ gw,
                        u16* __restrict__ T4t, u16* __restrict__ Tt2,
                        u16* __restrict__ Gt, u16* __restrict__ Gt2){
  int idx = blockIdx.x*256 + threadIdx.x;   // < 32768
  { int c=idx>>12, b=(idx>>6)&63, a=idx&63; T4t[idx] = f2b(T[(a*64+b)*8+c]); }
  { int c=idx>>12, a=(idx>>6)&63, b=idx&63; Tt2[idx] = f2b(T[(a*64+b)*8+c]); }
  if(idx < 4096){
    int a=idx>>6, j=idx&63;
    Gt[idx]  = f2b(gw[j*64+a]);   // Gt[a][j]
    Gt2[idx] = f2b(gw[idx]);      // Gt2[j][a]
  }
}

// ---- k0: unary = (x+pe)*m1 ; qzstate = unary ; mf = mask as float ----
__global__ void k0_init(const float* __restrict__ x, const int* __restrict__ mask,
                        float* __restrict__ unary, float* __restrict__ qzstate,
                        float* __restrict__ mf){
  int idx = blockIdx.x*256 + threadIdx.x;
  int d = idx & 63; int row = idx >> 6;
  int pos = row & (LL-1);
  int k2 = d & ~1;
  float div = __expf(-(float)k2 * 0.14391156962f);  // ln(10000)/64
  float arg = (float)pos * div;
  float pe = (d & 1) ? cosf(arg) : sinf(arg);
  float mk = (mask[row] != 0) ? 1.f : 0.f;
  float u = (x[idx] + pe) * mk;
  unary[idx] = u; qzstate[idx] = u;
  if(d == 0) mf[row] = mk;
}

// ---- kA: softmax64 -> qzb ; P2 softmax + Mg = P2@gw -> MgF ----
__global__ __launch_bounds__(256) void kA(const float* __restrict__ qzstate,
      const int* __restrict__ mask, const u16* __restrict__ Gt2, const u16* __restrict__ Gt,
      u16* __restrict__ qzb, float* __restrict__ MgF){
  __shared__ u16 qlds[64*72];
  __shared__ u16 P2s[64*72];
  int bid = blockIdx.x; int z = bid & 7, itile = bid >> 3;   // z-affine for XCD L2
  int t = threadIdx.x, lane = t&63, w = t>>6, l15 = lane&15, lhi = lane>>4;
  int rbase = z*LL + itile*64;
  for(int p=0;p<16;p++){
    int rl = w*16 + p, rg = rbase + rl;
    float v = qzstate[(size_t)rg*64 + lane];
    float mx = wred_max(v);
    float e = __expf(v - mx);
    float s = wred_sum(e);
    float mk = (mask[rg] != 0) ? 1.f : 0.f;
    u16 q = f2b(e/s*mk);
    qzb[(size_t)rg*64 + lane] = q;
    qlds[rl*72 + lane] = q;
  }
  __syncthreads();
  // P2 = rowsoftmax(qz @ gw^T)  (logits bounded ~|gw| -> fixed-max exp)
  f32x4 f[4];
  {
    const u16* Ar = &qlds[(w*16 + l15)*72 + lhi*8];
    bf16x8 a0 = ldb8(Ar), a1 = ldb8(Ar+32);
    #pragma unroll
    for(int ct=0;ct<4;ct++){
      const u16* Br = Gt2 + (size_t)(ct*16 + l15)*64 + lhi*8;
      f32x4 acc = {0.f,0.f,0.f,0.f};
      acc = MFMA(a0, ldb8(Br), acc);
      acc = MFMA(a1, ldb8(Br+32), acc);
      f[ct] = acc;
    }
  }
  #pragma unroll
  for(int jj=0;jj<4;jj++){
    float ps = 0.f;
    #pragma unroll
    for(int ct=0;ct<4;ct++){ float e = __expf(f[ct][jj]); f[ct][jj] = e; ps += e; }
    float s = g16_sum(ps);
    float iv = 1.f/s;
    #pragma unroll
    for(int ct=0;ct<4;ct++)
      P2s[(w*16 + lhi*4 + jj)*72 + ct*16 + l15] = f2b(f[ct][jj]*iv);
  }
  __syncthreads();
  // Mg[i,a] = sum_j P2[i,j] gw[j,a]  (B = Gt[a][j])
  {
    const u16* Ar = &P2s[(w*16 + l15)*72 + lhi*8];
    bf16x8 a0 = ldb8(Ar), a1 = ldb8(Ar+32);
    #pragma unroll
    for(int nt=0;nt<4;nt++){
      const u16* Br = Gt + (size_t)(nt*16 + l15)*64 + lhi*8;
      f32x4 acc = {0.f,0.f,0.f,0.f};
      acc = MFMA(a0, ldb8(Br), acc);
      acc = MFMA(a1, ldb8(Br+32), acc);
      #pragma unroll
      for(int jj=0;jj<4;jj++)
        MgF[((size_t)rbase + w*16 + lhi*4 + jj)*64 + nt*16 + l15] = acc[jj];
    }
  }
}

// ---- k2: per (z,c): t1[i][b], t1t[b][i], t2t[a][j]  (all K=64 GEMMs) ----
__global__ __launch_bounds__(256) void k2(const u16* __restrict__ qzb,
      const u16* __restrict__ T4t, const u16* __restrict__ Tt2,
      u16* __restrict__ t1b, u16* __restrict__ t1t, u16* __restrict__ t2t){
  int bid = blockIdx.x; int z = bid&7, c = (bid>>3)&7, itile = bid>>6;
  int zc = z*8 + c;
  int t = threadIdx.x, lane = t&63, w = t>>6, l15 = lane&15, lhi = lane>>4;
  int i0 = itile*64;
  const u16* qA = qzb + ((size_t)z*LL + i0 + w*16 + l15)*64 + lhi*8;
  bf16x8 qa0 = ldb8(qA), qa1 = ldb8(qA+32);
  const u16* tA = T4t + c*4096 + (w*16 + l15)*64 + lhi*8;
  bf16x8 ta0 = ldb8(tA), ta1 = ldb8(tA+32);
  const u16* uA = Tt2 + c*4096 + (w*16 + l15)*64 + lhi*8;
  bf16x8 ua0 = ldb8(uA), ua1 = ldb8(uA+32);
  #pragma unroll
  for(int nt=0;nt<4;nt++){
    { // t1 = qz @ T_c : B rows = T4t[c][b][a]
      const u16* Br = T4t + c*4096 + (nt*16 + l15)*64 + lhi*8;
      f32x4 acc = {0.f,0.f,0.f,0.f};
      acc = MFMA(qa0, ldb8(Br), acc);
      acc = MFMA(qa1, ldb8(Br+32), acc);
      #pragma unroll
      for(int jj=0;jj<4;jj++)
        t1b[((size_t)zc*LL + i0 + w*16 + lhi*4 + jj)*64 + nt*16 + l15] = f2b(acc[jj]);
    }
    const u16* Br = qzb + ((size_t)z*LL + i0 + nt*16 + l15)*64 + lhi*8;
    bf16x8 qb0 = ldb8(Br), qb1 = ldb8(Br+32);
    { // t1t[b][i]
      f32x4 acc = {0.f,0.f,0.f,0.f};
      acc = MFMA(ta0, qb0, acc);
      acc = MFMA(ta1, qb1, acc);
      #pragma unroll
      for(int jj=0;jj<4;jj++)
        t1t[((size_t)zc*64 + w*16 + lhi*4 + jj)*LL + i0 + nt*16 + l15] = f2b(acc[jj]);
    }
    { // t2t[a][j]
      f32x4 acc = {0.f,0.f,0.f,0.f};
      acc = MFMA(ua0, qb0, acc);
      acc = MFMA(ua1, qb1, acc);
      #pragma unroll
      for(int jj=0;jj<4;jj++)
        t2t[((size_t)zc*64 + w*16 + lhi*4 + jj)*LL + i0 + nt*16 + l15] = f2b(acc[jj]);
    }
  }
}

// ---- kF: fused S -> P -> mi = P@t2t (complete) + mj-partials = P^T@t1t ----
// grid: 256 blocks = (it4, c8, z8) with z = bid&7 ; 1024 threads (16 waves)
__global__ __launch_bounds__(1024) void kF(const u16* __restrict__ t1b, const u16* __restrict__ qzb,
        const u16* __restrict__ t1t, const u16* __restrict__ t2t, const float* __restrict__ mf,
        u16* __restrict__ miP, u16* __restrict__ mjP){
  extern __shared__ char smem[];
  u16*   Pp   = (u16*)smem;                   // [32][520]   33280 B
  u16*   PpT  = (u16*)(smem + 33280);         // [512][40]   40960 B
  float* red  = (float*)(smem + 74240);       // [32][16]     2048 B
  float* stgf = (float*)(smem + 76288);       // [2][32][68] f32 (17408 B)
  u16*   stg  = (u16*)(smem + 76288);         // [128][72] u16   (18432 B)
  int bid = blockIdx.x;
  int z = bid&7, c = (bid>>3)&7, it = bid>>6;   // it < 4
  int zc = z*8 + c;
  int t = threadIdx.x, lane = t&63, w = t>>6, l15 = lane&15, lhi = lane>>4;
  int jc0 = w*32;                               // wave's j-slice
  float mfj[2];
  mfj[0] = mf[z*LL + jc0 + l15];
  mfj[1] = mf[z*LL + jc0 + 16 + l15];
  f32x4 mj[2][4];
  #pragma unroll
  for(int jt=0;jt<2;jt++)
    #pragma unroll
    for(int bt=0;bt<4;bt++) mj[jt][bt] = (f32x4){0.f,0.f,0.f,0.f};

  for(int ip=0; ip<4; ++ip){
    int i0g = it*128 + ip*32;
    // ---- S panel (32 rows x wave's 32 cols) ----
    f32x4 S[2][2];
    #pragma unroll
    for(int rt=0;rt<2;rt++){ S[rt][0] = (f32x4){0,0,0,0}; S[rt][1] = (f32x4){0,0,0,0}; }
    bf16x8 a0[2], a1[2];
    #pragma unroll
    for(int rt=0;rt<2;rt++){
      const u16* Ar = t1b + ((size_t)zc*LL + i0g + rt*16 + l15)*64 + lhi*8;
      a0[rt] = ldb8(Ar); a1[rt] = ldb8(Ar+32);
    }
    #pragma unroll
    for(int ct=0;ct<2;ct++){
      const u16* Br = qzb + ((size_t)z*LL + jc0 + ct*16 + l15)*64 + lhi*8;
      bf16x8 b0 = ldb8(Br), b1 = ldb8(Br+32);
      #pragma unroll
      for(int rt=0;rt<2;rt++){
        S[rt][ct] = MFMA(a0[rt], b0, S[rt][ct]);
        S[rt][ct] = MFMA(a1[rt], b1, S[rt][ct]);
      }
    }
    // ---- mask/diag/exp (fixed max), partial row-sums ----
    #pragma unroll
    for(int rt=0;rt<2;rt++)
      #pragma unroll
      for(int jj=0;jj<4;jj++){
        int rloc = rt*16 + lhi*4 + jj;
        int irow = i0g + rloc;
        float mfi = mf[z*LL + irow];
        float ps = 0.f;
        #pragma unroll
        for(int ct=0;ct<2;ct++){
          int jcol = jc0 + ct*16 + l15;
          float v = S[rt][ct][jj] - ((irow==jcol)?BIGV:0.f);
          float e = mfi * mfj[ct] * __expf(v);
          S[rt][ct][jj] = e; ps += e;
        }
        ps = g16_sum(ps);
        if(l15 == 0) red[rloc*16 + w] = ps;
      }
    __syncthreads();
    // ---- normalize, write Pp (row-major) + PpT (transposed) ----
    #pragma unroll
    for(int rt=0;rt<2;rt++){
      float iv[4];
      #pragma unroll
      for(int jj=0;jj<4;jj++){
        const float* rp = &red[(rt*16 + lhi*4 + jj)*16];
        f32x4 s0 = *(const f32x4*)rp,      s1 = *(const f32x4*)(rp+4);
        f32x4 s2 = *(const f32x4*)(rp+8),  s3 = *(const f32x4*)(rp+12);
        float s = (s0[0]+s0[1]+s0[2]+s0[3]) + (s1[0]+s1[1]+s1[2]+s1[3])
                + (s2[0]+s2[1]+s2[2]+s2[3]) + (s3[0]+s3[1]+s3[2]+s3[3]);
        iv[jj] = s > 0.f ? 1.f/s : 0.f;
      }
      #pragma unroll
      for(int ct=0;ct<2;ct++){
        int jcol = jc0 + ct*16 + l15;
        u16 p4[4];
        #pragma unroll
        for(int jj=0;jj<4;jj++){
          u16 pb = f2b(S[rt][ct][jj]*iv[jj]);
          Pp[(rt*16 + lhi*4 + jj)*520 + jcol] = pb;
          p4[jj] = pb;
        }
        s16x4 v4 = {(short)p4[0],(short)p4[1],(short)p4[2],(short)p4[3]};
        *(s16x4*)&PpT[(size_t)jcol*40 + rt*16 + lhi*4] = v4;
      }
    }
    __syncthreads();
    // ---- mi: (h,wr,wc) split, half-K each; partials to stgf ----
    {
      int h = w>>3, wr = (w>>2)&1, wc = w&3;
      f32x4 mia = {0.f,0.f,0.f,0.f};
      const u16* Ab = Pp + (wr*16 + l15)*520 + h*256 + lhi*8;
      const u16* Bb = t2t + ((size_t)zc*64 + wc*16 + l15)*LL + h*256 + lhi*8;
      #pragma unroll
      for(int ks=0;ks<8;ks++)
        mia = MFMA(ldb8(Ab + ks*32), ldb8(Bb + ks*32), mia);
      #pragma unroll
      for(int jj=0;jj<4;jj++)
        stgf[(h*32 + wr*16 + lhi*4 + jj)*68 + wc*16 + l15] = mia[jj];
    }
    // ---- mj accumulate: K=32 (this panel), A = PpT, B = t1t ----
    {
      bf16x8 av[2];
      #pragma unroll
      for(int jt=0;jt<2;jt++)
        av[jt] = ldb8(PpT + (size_t)(jc0 + jt*16 + l15)*40 + lhi*8);
      #pragma unroll
      for(int bt=0;bt<4;bt++){
        bf16x8 b = ldb8(t1t + ((size_t)zc*64 + bt*16 + l15)*LL + i0g + lhi*8);
        #pragma unroll
        for(int jt=0;jt<2;jt++) mj[jt][bt] = MFMA(av[jt], b, mj[jt][bt]);
      }
    }
    __syncthreads();
    // ---- mi store: sum 2 K-halves, 16B coalesced ----
    if(t < 512){
      int r = t>>4, cc = t&15;
      f32x4 v0 = *(const f32x4*)&stgf[r*68 + cc*4];
      f32x4 v1 = *(const f32x4*)&stgf[(32+r)*68 + cc*4];
      s16x4 o = { (short)f2b(v0[0]+v1[0]), (short)f2b(v0[1]+v1[1]),
                  (short)f2b(v0[2]+v1[2]), (short)f2b(v0[3]+v1[3]) };
      *(s16x4*)&miP[((size_t)z*LL + i0g + r)*512 + c*64 + cc*4] = o;
    }
    __syncthreads();
  }
  // ---- mj dump: 4 rounds of 128 j-rows via LDS, 16B coalesced ----
  for(int r=0;r<4;r++){
    if((w>>2) == r){
      int jl = (w&3)*32;
      #pragma unroll
      for(int jt=0;jt<2;jt++)
        #pragma unroll
        for(int bt=0;bt<4;bt++)
          #pragma unroll
          for(int jj=0;jj<4;jj++)
            stg[(jl + jt*16 + lhi*4 + jj)*72 + bt*16 + l15] = f2b(mj[jt][bt][jj]);
    }
    __syncthreads();
    {
      int jr = t>>3, ch = t&7;
      *(bf16x8*)&mjP[(((size_t)(it*8 + z))*LL + r*128 + jr)*512 + c*64 + ch*8]
        = *(const bf16x8*)&stg[jr*72 + ch*8];
    }
    __syncthreads();
  }
}

// ---- k5c: out = (unary + Mg + sum_c miP + sum_{it,c} mjP) * m1  (elementwise) ----
__global__ __launch_bounds__(256) void k5c(const u16* __restrict__ miP, const u16* __restrict__ mjP,
      const float* __restrict__ MgF, const float* __restrict__ unary, const float* __restrict__ mf,
      float* __restrict__ outq){
  int bid = blockIdx.x; int z = bid&7, itile = bid>>3;   // itile < 32
  int t = threadIdx.x;
  int r = t>>4, cc = t&15;
  int row = itile*16 + r;
  size_t gr = (size_t)z*LL + row;
  f32x4 acc = *(const f32x4*)&MgF[gr*64 + cc*4];
  #pragma unroll
  for(int c=0;c<8;c++){
    s16x4 v = *(const s16x4*)&miP[gr*512 + c*64 + cc*4];
    acc[0] += b2f((u16)v[0]); acc[1] += b2f((u16)v[1]);
    acc[2] += b2f((u16)v[2]); acc[3] += b2f((u16)v[3]);
  }
  #pragma unroll
  for(int s=0;s<4;s++)
    #pragma unroll
    for(int c=0;c<8;c++){
      s16x4 v = *(const s16x4*)&mjP[(((size_t)(s*8 + z))*LL + row)*512 + c*64 + cc*4];
      acc[0] += b2f((u16)v[0]); acc[1] += b2f((u16)v[1]);
      acc[2] += b2f((u16)v[2]); acc[3] += b2f((u16)v[3]);
    }
  f32x4 u = *(const f32x4*)&unary[gr*64 + cc*4];
  float mk = mf[gr];
  f32x4 o;
  #pragma unroll
  for(int k=0;k<4;k++) o[k] = (u[k] + acc[k]) * mk;
  *(f32x4*)&outq[gr*64 + cc*4] = o;
}

extern "C" void kernel_launch(void* const* d_in, const int* in_sizes, int n_in,
                              void* d_out, int out_size, void* d_ws, size_t ws_size,
                              hipStream_t stream) {
  const float* x       = (const float*)d_in[0];
  const int*   mask    = (const int*)d_in[1];
  const float* ternary = (const float*)d_in[2];
  const float* gw      = (const float*)d_in[3];
  float* out = (float*)d_out;

  const size_t NE = (size_t)BB*LL*64;          // 262144
  char* p = (char*)d_ws;
  auto alloc = [&](size_t bytes)->void*{
    void* r = (void*)p; p += (bytes + 255) & ~(size_t)255; return r;
  };
  float* unary   = (float*)alloc(NE*4);
  float* qzstate = (float*)alloc(NE*4);
  float* mf      = (float*)alloc((size_t)BB*LL*4);
  u16*   qzb     = (u16*)alloc(NE*2);
  u16*   t1b     = (u16*)alloc((size_t)BB*HH*LL*64*2);   // 4.2 MB
  u16*   t1t     = (u16*)alloc((size_t)BB*HH*LL*64*2);   // 4.2 MB
  u16*   t2t     = (u16*)alloc((size_t)BB*HH*LL*64*2);   // 4.2 MB
  float* MgF     = (float*)alloc(NE*4);                  // 1 MB
  u16*   miP     = (u16*)alloc((size_t)BB*LL*512*2);     // 4.2 MB
  u16*   mjP     = (u16*)alloc((size_t)32*LL*512*2);     // 16.8 MB
  u16*   T4t     = (u16*)alloc(32768*2);
  u16*   Tt2     = (u16*)alloc(32768*2);
  u16*   Gt      = (u16*)alloc(4096*2);
  u16*   Gt2     = (u16*)alloc(4096*2);

  const int KF_LDS = 94720;
  hipFuncSetAttribute(reinterpret_cast<const void*>(kF),
                      hipFuncAttributeMaxDynamicSharedMemorySize, KF_LDS);

  kp_prep<<<128, 256, 0, stream>>>(ternary, gw, T4t, Tt2, Gt, Gt2);
  k0_init<<<(int)(NE/256), 256, 0, stream>>>(x, mask, unary, qzstate, mf);
  for(int it=0; it<4; ++it){
    kA<<<BB*8, 256, 0, stream>>>(qzstate, mask, Gt2, Gt, qzb, MgF);
    k2<<<512, 256, 0, stream>>>(qzb, T4t, Tt2, t1b, t1t, t2t);
    kF<<<256, 1024, KF_LDS, stream>>>(t1b, qzb, t1t, t2t, mf, miP, mjP);
    float* outq = (it==3) ? out : qzstate;
    k5c<<<256, 256, 0, stream>>>(miP, mjP, MgF, unary, mf, outq);
  }
}